// Round 6
// baseline (412.169 us; speedup 1.0000x reference)
//
#include <hip/hip_runtime.h>

#define SEQ    256
#define BATCHN 2048
#define NIN    64
#define H      128
#define NOUT   64
#define TOUT   128
#define BT     8      // batch rows per block -> 256 blocks, full chip
#define ASTR   200    // LDS A-row stride in halfs (192 + 8 pad)
#define TCH    16     // decoder steps buffered before a coalesced flush

using half8 = _Float16 __attribute__((ext_vector_type(8)));
using f32x4 = float    __attribute__((ext_vector_type(4)));

__device__ __forceinline__ float sigf(float v) {
    return __builtin_amdgcn_rcpf(1.f + __expf(-v));
}
__device__ __forceinline__ float tanhfast(float v) {
    return 1.f - 2.f * __builtin_amdgcn_rcpf(1.f + __expf(2.f * v));
}

__device__ __forceinline__ half8 ldfrag8(const float* __restrict__ p) {
    half8 r;
#pragma unroll
    for (int e = 0; e < 8; ++e) r[e] = (_Float16)p[e];
    return r;
}

// lstm elementwise on one (row,hcol) pair given packed gates {i,f,g,o}
__device__ __forceinline__ float lstm_cell(const f32x4 g, float& c) {
    const float ig = sigf(g[0]);
    const float fg = sigf(g[1]);
    const float gg = tanhfast(g[2]);
    const float og = sigf(g[3]);
    c = fg * c + ig * gg;
    return og * tanhfast(c);
}

// Full-chip fused seq2seq: 256 blocks x BT=8. MFMA produces gates in D-layout
// (rows 4*lg+r valid for lg<2); gates are re-balanced through LDS (packed f32x4
// per (row,hcol)) so ALL 512 lanes do equal elementwise work (2 pairs each, c-state
// register-resident with fixed ownership across all 384 steps).
__global__ __launch_bounds__(512, 2) void seq2seq_fused(
    const float* __restrict__ x,
    const float* __restrict__ eWih, const float* __restrict__ eWhh, const float* __restrict__ eb,
    const float* __restrict__ dWih, const float* __restrict__ dWhh, const float* __restrict__ db,
    const float* __restrict__ oW,   const float* __restrict__ obv,
    float* __restrict__ out)
{
    __shared__ __align__(16) _Float16 als[2][16][ASTR];   // A staging: rows 0..7 live, 8..15 zero
    __shared__ __align__(16) float    gbuf[BT][H][4];     // staged gates [row][hcol][{i,f,g,o}]
    __shared__ __align__(16) _Float16 ybuf[TCH][BT][68];  // staged decoder outputs

    const int tid  = threadIdx.x;
    const int lane = tid & 63;
    const int w    = tid >> 6;      // wave 0..7 (col slice 16w..16w+15)
    const int jl   = lane & 15;
    const int lg   = lane >> 4;
    const int b0   = blockIdx.x * BT;

    // elementwise ownership: lane owns pairs (er0,ec) and (er1,ec)
    const int er0 = tid >> 7;        // rows 0..3
    const int er1 = er0 + 4;         // rows 4..7
    const int ec  = tid & 127;       // hcol 0..127
    float c2[2] = {0.f, 0.f};        // register-resident cell state, fixed ownership

    // ---------------- encoder weights -> resident VGPR fragments ----------------
    half8 wf[4][6];
    float bq[4];
#pragma unroll
    for (int q = 0; q < 4; ++q) {
        const int j = q * H + w * 16 + jl;
#pragma unroll
        for (int kc = 0; kc < 2; ++kc)
            wf[q][kc] = ldfrag8(eWih + j * NIN + kc * 32 + lg * 8);
#pragma unroll
        for (int kc = 2; kc < 6; ++kc)
            wf[q][kc] = ldfrag8(eWhh + j * H + (kc - 2) * 32 + lg * 8);
        bq[q] = eb[j];
    }

    // zero both A buffers (rows 8..15 stay zero forever)
    for (int i = tid; i < 2 * 16 * ASTR; i += 512) ((_Float16*)als)[i] = (_Float16)0.f;
    __syncthreads();
    // stage x_0: 8 rows x 64 cols = 512 elems, one per thread
    {
        const int xi = tid >> 6, xn = tid & 63;
        als[0][xi][xn] = (_Float16)x[(b0 + xi) * NIN + xn];
    }
    __syncthreads();

    // ---------------- encoder: 256 steps, 2 barriers/step ----------------
    for (int t = 0; t < SEQ; ++t) {
        const int cur = t & 1, nxt = cur ^ 1;

        const int xi = tid >> 6, xn = tid & 63;
        float xv = 0.f;
        if (t + 1 < SEQ)
            xv = x[((t + 1) * BATCHN + b0 + xi) * NIN + xn];

        half8 af[6];
#pragma unroll
        for (int kc = 0; kc < 6; ++kc)
            af[kc] = *(const half8*)&als[cur][jl][kc * 32 + lg * 8];

        f32x4 ac[4];
#pragma unroll
        for (int q = 0; q < 4; ++q) {
            f32x4 a = {bq[q], bq[q], bq[q], bq[q]};
#pragma unroll
            for (int kc = 0; kc < 6; ++kc)
                a = __builtin_amdgcn_mfma_f32_16x16x32_f16(af[kc], wf[q][kc], a, 0, 0, 0);
            ac[q] = a;
        }

        // stage gates: valid rows are 4*lg+r < 8 -> lg<2
        if (lg < 2) {
#pragma unroll
            for (int r = 0; r < 4; ++r) {
                f32x4 g = {ac[0][r], ac[1][r], ac[2][r], ac[3][r]};
                *(f32x4*)&gbuf[lg * 4 + r][w * 16 + jl][0] = g;
            }
        }
        __syncthreads();

        // balanced elementwise: 2 pairs per lane
        {
            const f32x4 g0 = *(const f32x4*)&gbuf[er0][ec][0];
            const f32x4 g1 = *(const f32x4*)&gbuf[er1][ec][0];
            const float h0 = lstm_cell(g0, c2[0]);
            const float h1 = lstm_cell(g1, c2[1]);
            als[nxt][er0][NIN + ec] = (_Float16)h0;
            als[nxt][er1][NIN + ec] = (_Float16)h1;
        }
        als[nxt][xi][xn] = (_Float16)xv;   // x_{t+1} (zeros after last -> decoder x0)
        __syncthreads();
    }

    // ---------------- decoder weights (reuse registers) ----------------
#pragma unroll
    for (int q = 0; q < 4; ++q) {
        const int j = q * H + w * 16 + jl;
#pragma unroll
        for (int kc = 0; kc < 2; ++kc)
            wf[q][kc] = ldfrag8(dWih + j * NIN + kc * 32 + lg * 8);
#pragma unroll
        for (int kc = 2; kc < 6; ++kc)
            wf[q][kc] = ldfrag8(dWhh + j * H + (kc - 2) * 32 + lg * 8);
        bq[q] = db[j];
    }
    half8 of[4];
    float oB = 0.f;
    if (w < 4) {  // waves 0..3 own the y-GEMM (N_OUT = 64)
        const int j = w * 16 + jl;
#pragma unroll
        for (int kc = 0; kc < 4; ++kc)
            of[kc] = ldfrag8(oW + j * H + kc * 32 + lg * 8);
        oB = obv[j];
    }

    // ---------------- decoder: 128 steps, 3 barriers/step ----------------
    for (int s = 0; s < TOUT; ++s) {
        const int cur = s & 1, nxt = cur ^ 1;

        half8 af[6];
#pragma unroll
        for (int kc = 0; kc < 6; ++kc)
            af[kc] = *(const half8*)&als[cur][jl][kc * 32 + lg * 8];

        f32x4 ac[4];
#pragma unroll
        for (int q = 0; q < 4; ++q) {
            f32x4 a = {bq[q], bq[q], bq[q], bq[q]};
#pragma unroll
            for (int kc = 0; kc < 6; ++kc)
                a = __builtin_amdgcn_mfma_f32_16x16x32_f16(af[kc], wf[q][kc], a, 0, 0, 0);
            ac[q] = a;
        }

        if (lg < 2) {
#pragma unroll
            for (int r = 0; r < 4; ++r) {
                f32x4 g = {ac[0][r], ac[1][r], ac[2][r], ac[3][r]};
                *(f32x4*)&gbuf[lg * 4 + r][w * 16 + jl][0] = g;
            }
        }
        __syncthreads();

        {
            const f32x4 g0 = *(const f32x4*)&gbuf[er0][ec][0];
            const f32x4 g1 = *(const f32x4*)&gbuf[er1][ec][0];
            const float h0 = lstm_cell(g0, c2[0]);
            const float h1 = lstm_cell(g1, c2[1]);
            als[nxt][er0][NIN + ec] = (_Float16)h0;
            als[nxt][er1][NIN + ec] = (_Float16)h1;
        }
        __syncthreads();  // h(s) complete

        if (w < 4) {
            half8 hf[4];
#pragma unroll
            for (int kc = 0; kc < 4; ++kc)
                hf[kc] = *(const half8*)&als[nxt][jl][NIN + kc * 32 + lg * 8];
            f32x4 ya = {oB, oB, oB, oB};
#pragma unroll
            for (int kc = 0; kc < 4; ++kc)
                ya = __builtin_amdgcn_mfma_f32_16x16x32_f16(hf[kc], of[kc], ya, 0, 0, 0);
            if (lg < 2) {
                const int j = w * 16 + jl;
                const int tt = s & (TCH - 1);
#pragma unroll
                for (int r = 0; r < 4; ++r) {
                    const int row = lg * 4 + r;
                    const float yv = ya[r];
                    als[nxt][row][j] = (_Float16)yv;   // feedback -> next x_t
                    ybuf[tt][row][j] = (_Float16)yv;   // staged output
                }
            }
        }
        __syncthreads();  // y visible before next gate GEMM; orders ybuf for flush

        // coalesced flush every TCH steps: full 64B lines along t
        if ((s & (TCH - 1)) == (TCH - 1)) {
            const int t0 = s & ~(TCH - 1);
#pragma unroll
            for (int it = 0; it < 4; ++it) {
                const int slot = it * 512 + tid;   // 0..2047
                const int pair = slot >> 2;        // (row,j): 0..511
                const int tq   = slot & 3;
                const int row  = pair >> 6;
                const int j    = pair & 63;
                float4 v;
                v.x = (float)ybuf[tq * 4 + 0][row][j];
                v.y = (float)ybuf[tq * 4 + 1][row][j];
                v.z = (float)ybuf[tq * 4 + 2][row][j];
                v.w = (float)ybuf[tq * 4 + 3][row][j];
                *(float4*)(out + ((size_t)(b0 + row) * NOUT + j) * TOUT + t0 + tq * 4) = v;
            }
            // flush (pre-B1 of next step) strictly precedes next ybuf writes (post-B2)
        }
    }
}

extern "C" void kernel_launch(void* const* d_in, const int* in_sizes, int n_in,
                              void* d_out, int out_size, void* d_ws, size_t ws_size,
                              hipStream_t stream) {
    (void)in_sizes; (void)n_in; (void)out_size; (void)d_ws; (void)ws_size;
    const float* x    = (const float*)d_in[0];
    const float* eWih = (const float*)d_in[1];
    const float* eWhh = (const float*)d_in[2];
    const float* eb   = (const float*)d_in[3];
    const float* dWih = (const float*)d_in[4];
    const float* dWhh = (const float*)d_in[5];
    const float* db   = (const float*)d_in[6];
    const float* oW   = (const float*)d_in[7];
    const float* ob   = (const float*)d_in[8];

    seq2seq_fused<<<BATCHN / BT, 512, 0, stream>>>(
        x, eWih, eWhh, eb, dWih, dWhh, db, oW, ob, (float*)d_out);
}